// Round 16
// baseline (592.551 us; speedup 1.0000x reference)
//
#include <hip/hip_runtime.h>

#define Bn 32
#define Tn 512
#define Dn 512
#define Vn 512

typedef float f4 __attribute__((ext_vector_type(4)));
typedef int i8v __attribute__((ext_vector_type(8)));
typedef _Float16 h8f __attribute__((ext_vector_type(8)));
typedef _Float16 h4f __attribute__((ext_vector_type(4)));

__device__ __forceinline__ float max8lds(const float* p) {
  float4 a = *(const float4*)p;
  float4 b = *(const float4*)(p + 4);
  return fmaxf(fmaxf(fmaxf(a.x, a.y), fmaxf(a.z, a.w)),
               fmaxf(fmaxf(b.x, b.y), fmaxf(b.z, b.w)));
}

// 64-lane max via DPP (row_shr 1/2/4/8 + bcast15/31), result broadcast via readlane
__device__ __forceinline__ float dpp64max(float x) {
  int t;
  t = __builtin_amdgcn_update_dpp(__float_as_int(x), __float_as_int(x), 0x111, 0xF, 0xF, false);
  x = fmaxf(x, __int_as_float(t));
  t = __builtin_amdgcn_update_dpp(__float_as_int(x), __float_as_int(x), 0x112, 0xF, 0xF, false);
  x = fmaxf(x, __int_as_float(t));
  t = __builtin_amdgcn_update_dpp(__float_as_int(x), __float_as_int(x), 0x114, 0xF, 0xF, false);
  x = fmaxf(x, __int_as_float(t));
  t = __builtin_amdgcn_update_dpp(__float_as_int(x), __float_as_int(x), 0x118, 0xF, 0xF, false);
  x = fmaxf(x, __int_as_float(t));
  t = __builtin_amdgcn_update_dpp(__float_as_int(x), __float_as_int(x), 0x142, 0xF, 0xF, false);
  x = fmaxf(x, __int_as_float(t));
  t = __builtin_amdgcn_update_dpp(__float_as_int(x), __float_as_int(x), 0x143, 0xF, 0xF, false);
  x = fmaxf(x, __int_as_float(t));
  return __int_as_float(__builtin_amdgcn_readlane(__float_as_int(x), 63));
}

// raw barrier: LDS-visibility only (no vmcnt drain -> global ops float across steps)
__device__ __forceinline__ void bar_lgkm() {
  asm volatile("s_waitcnt lgkmcnt(0)" ::: "memory");
  __builtin_amdgcn_s_barrier();
}

// ---- f32 -> OCP e4m3fn, round-to-nearest-even (x >= 0 assumed) ----
__device__ __forceinline__ unsigned int f32_to_e4m3(float x) {
  x = fminf(x, 448.0f);
  unsigned int bits = __float_as_uint(x);
  int e = (int)((bits >> 23) & 0xFF) - 127;
  if (e < -6) {
    return (unsigned int)__float2int_rn(x * 512.0f);
  }
  unsigned int man = bits & 0x7FFFFF;
  int te = e + 7;
  unsigned int r = man >> 20;
  unsigned int rem = man & 0xFFFFF;
  if (rem > 0x80000u || (rem == 0x80000u && (r & 1u))) r++;
  if (r == 8u) { r = 0u; te++; }
  if (te > 15) { te = 15; r = 6u; }
  unsigned int byte = ((unsigned int)te << 3) | r;
  if (byte > 0x7Eu) byte = 0x7Eu;
  return byte;
}

// fast path: HW packed fp8 convert (branch-free); fallback = software RNE
__device__ __forceinline__ unsigned int cvt_e4m3_fast(float p) {
#if __has_builtin(__builtin_amdgcn_cvt_pk_fp8_f32)
  return (unsigned int)(__builtin_amdgcn_cvt_pk_fp8_f32(p, p, 0, false) & 0xFF);
#else
  return f32_to_e4m3(p);
#endif
}

// ---- pruning radius: max over columns v of (max_u T[u][v] - min_u T[u][v]) ----
__global__ __launch_bounds__(512) void crf_minmax(const float* __restrict__ trans,
                                                  unsigned int* __restrict__ Rout) {
  __shared__ float smn[8][64], smx[8][64];
  const int c = threadIdx.x & 63;
  const int seg = threadIdx.x >> 6;
  const int col = (int)blockIdx.x * 64 + c;
  float mn = 3e38f, mx = -3e38f;
#pragma unroll 4
  for (int u = seg * 64; u < seg * 64 + 64; ++u) {
    float t = trans[(size_t)u * Vn + col];
    mn = fminf(mn, t); mx = fmaxf(mx, t);
  }
  smn[seg][c] = mn; smx[seg][c] = mx;
  __syncthreads();
  if (seg == 0) {
#pragma unroll
    for (int i = 1; i < 8; ++i) { mn = fminf(mn, smn[i][c]); mx = fmaxf(mx, smx[i][c]); }
    float r = dpp64max(mx - mn);  // r >= 0
    if (c == 0) atomicMax((int*)Rout, __float_as_int(r));
  }
}

// ---- E8: exp(trans) as fp8 e4m3 MFMA A-fragments for 16x16x128 ----
__global__ __launch_bounds__(256) void crf_build_E8(const float* __restrict__ trans,
                                                    unsigned char* __restrict__ E8) {
  const int fid = (int)blockIdx.x;       // 0..127 = vt*4 + kc
  const int vt = fid >> 2, kc = fid & 3;
  const int t = threadIdx.x;             // 8 bytes per thread
  const int lane = t >> 2;
  const int j0 = (t & 3) * 8;
  const int v = vt * 16 + (lane & 15);
  const int ubase = kc * 128 + (lane >> 4) * 32 + j0;
  unsigned long long pack = 0;
#pragma unroll
  for (int s = 0; s < 8; ++s) {
    float e = __expf(trans[(size_t)(ubase + s) * Vn + v]);
    pack |= (unsigned long long)f32_to_e4m3(e) << (8 * s);
  }
  *(unsigned long long*)(E8 + (size_t)fid * 2048 + lane * 32 + j0) = pack;
}

// ---- W pre-split: W -> f16 head (WH) + f16 residual (WL), elementwise ----
__global__ __launch_bounds__(256) void crf_wsplit(const float* __restrict__ Wt,
                                                  _Float16* __restrict__ WH,
                                                  _Float16* __restrict__ WL) {
  int i4 = (int)blockIdx.x * 256 + threadIdx.x;  // one float4 per thread
  float4 v = ((const float4*)Wt)[i4];
  float xs[4] = {v.x, v.y, v.z, v.w};
  _Float16 h[4], l[4];
#pragma unroll
  for (int i = 0; i < 4; ++i) {
    h[i] = (_Float16)xs[i];
    l[i] = (_Float16)(xs[i] - (float)h[i]);
  }
  *(h4f*)(WH + (size_t)i4 * 4) = *(h4f*)h;
  *(h4f*)(WL + (size_t)i4 * 4) = *(h4f*)l;
}

// ---- emissions via split-f16 MFMA (f32-accurate): BM=64, BN=512, BK=32 ----
// W halves preloaded from global (no per-block conversion); X split on the fly.
__global__ __launch_bounds__(256) void crf_gemm(const float* __restrict__ X,
                                                const _Float16* __restrict__ WH,
                                                const _Float16* __restrict__ WL,
                                                float* __restrict__ C) {
  __shared__ h8f XfH[4][64], XfL[4][64];    // 8 KB
  __shared__ h8f WfH[32][64], WfL[32][64];  // 64 KB
  const int tid = threadIdx.x;
  const int m0 = (int)blockIdx.x * 64;
  const int wv = tid >> 6, lane = tid & 63;
  const int g = lane >> 4, cc = lane & 15;
  const int srow = tid >> 2;                // 0..63
  const int sc0 = (tid & 3) * 8;            // k-chunk 0/8/16/24
  const int p = (tid & 3) * 16 + ((tid >> 2) & 15);  // fragment slot
  f4 acc[32];
#pragma unroll
  for (int i = 0; i < 32; ++i) acc[i] = (f4)(0.f);

  for (int k0 = 0; k0 < Dn; k0 += 32) {
    __syncthreads();
    {
      const float* xp = X + (size_t)(m0 + srow) * Dn + k0 + sc0;
      float4 xa = *(const float4*)xp;
      float4 xb = *(const float4*)(xp + 4);
      float xs[8] = {xa.x, xa.y, xa.z, xa.w, xb.x, xb.y, xb.z, xb.w};
      _Float16 hh[8], ll[8];
#pragma unroll
      for (int i = 0; i < 8; ++i) {
        hh[i] = (_Float16)xs[i];
        ll[i] = (_Float16)(xs[i] - (float)hh[i]);
      }
      XfH[tid >> 6][p] = *(h8f*)hh;
      XfL[tid >> 6][p] = *(h8f*)ll;
#pragma unroll
      for (int i = 0; i < 8; ++i) {
        int r = i * 64 + srow;
        WfH[i * 4 + (tid >> 6)][p] = *(const h8f*)(WH + (size_t)r * Dn + k0 + sc0);
        WfL[i * 4 + (tid >> 6)][p] = *(const h8f*)(WL + (size_t)r * Dn + k0 + sc0);
      }
    }
    __syncthreads();
    h8f aH = XfH[wv][lane];
    h8f aL = XfL[wv][lane];
#pragma unroll
    for (int nt = 0; nt < 32; ++nt) {
      h8f bH = WfH[nt][lane];
      h8f bL = WfL[nt][lane];
      acc[nt] = __builtin_amdgcn_mfma_f32_16x16x32_f16(aH, bH, acc[nt], 0, 0, 0);
      acc[nt] = __builtin_amdgcn_mfma_f32_16x16x32_f16(aH, bL, acc[nt], 0, 0, 0);
      acc[nt] = __builtin_amdgcn_mfma_f32_16x16x32_f16(aL, bH, acc[nt], 0, 0, 0);
      acc[nt] = __builtin_amdgcn_mfma_f32_16x16x32_f16(aL, bL, acc[nt], 0, 0, 0);
    }
  }
#pragma unroll
  for (int nt = 0; nt < 32; ++nt)
#pragma unroll
    for (int r = 0; r < 4; ++r)
      C[(size_t)(m0 + wv * 16 + 4 * g + r) * Vn + nt * 16 + cc] = acc[nt][r];
}

// ---- shared-memory union: forward vs viterbi roles ----
union SM {
  struct {
    __align__(16) unsigned char ph[Vn];   // fp8 p broadcast (512 B)
    __align__(16) float wred[8];
    __align__(16) float wred2[8];
    unsigned char padsh[Tn];
  } f;
  struct {
    __align__(16) float va2[2][Vn];
    __align__(16) unsigned short bpbuf[32][Vn];
    unsigned short tokens[Tn];
    __align__(16) float wvals[8];
    int widxs[8];
    unsigned char padsh[Tn];
    int lastS;
  } v;
};

// ---- fused scan: blocks 0..31 forward(logZ,loglik); 32..63 viterbi+backtrace ----
__global__ __launch_bounds__(512, 2) void crf_scan(
    const float* __restrict__ emis, const float* __restrict__ trans,
    const unsigned char* __restrict__ E8, const float* __restrict__ Rp,
    const int* __restrict__ tgt, const unsigned char* __restrict__ pad,
    unsigned short* __restrict__ bps, float* __restrict__ out_ll,
    float* __restrict__ out_tok) {
  __shared__ SM sm;

  const int tid = threadIdx.x;
  const int b = blockIdx.x & 31;
  const int role = blockIdx.x >> 5;
  const float* eb = emis + (size_t)b * Tn * Vn;
  const int w = tid >> 6;
  const int lane = tid & 63;

  if (role == 0) {
    // ========== FORWARD (MX-FP8 MFMA K=128, exact-m, 2-deep MFMA chains) ==========
    const int g = lane >> 4, c = lane & 15;
    const int t2sel = c >> 2, r2sel = c & 3;
    const int sidx = ((16 * ((lane >> 2) & 3)) + 4 * (lane >> 4) + (lane & 3)) << 2;
    i8v EA[4][4];
    {
      const i8v* E8v = (const i8v*)E8;
#pragma unroll
      for (int vt2 = 0; vt2 < 4; ++vt2)
#pragma unroll
        for (int kc = 0; kc < 4; ++kc)
          EA[vt2][kc] = E8v[((4 * w + vt2) * 4 + kc) * 64 + lane];
    }
    sm.f.padsh[tid] = pad[b * Tn + tid];
    float alphaR = eb[tid];
    float ecur = eb[Vn + tid];
    {
      float r = dpp64max(alphaR);
      if (lane == 0) sm.f.wred[w] = r;
    }
    bar_lgkm();
    float m = max8lds(sm.f.wred);  // exact max(alpha_{t-1})

    const f4 z4 = (f4)(0.f);
    for (int t = 1; t < Tn; ++t) {
      float p = __expf(alphaR - m);            // p in (0, 1]
      sm.f.ph[tid] = (unsigned char)cvt_e4m3_fast(p);
      bar_lgkm();  // A: ph visible
      float enext = (t + 1 < Tn) ? eb[(size_t)(t + 1) * Vn + tid] : 0.f;
      const uint4* phq = (const uint4*)sm.f.ph;
      i8v B4[4];
#pragma unroll
      for (int kc = 0; kc < 4; ++kc) {
        union { uint4 u[2]; i8v v; } bu;
        bu.u[0] = phq[kc * 8 + g * 2];
        bu.u[1] = phq[kc * 8 + g * 2 + 1];
        B4[kc] = bu.v;
      }
      // 8 accumulators, 2-deep chains (kc{0,1} -> A, kc{2,3} -> B), C=z4 init
      f4 aA0 = __builtin_amdgcn_mfma_scale_f32_16x16x128_f8f6f4(
          EA[0][0], B4[0], z4, 0, 0, 0, 0x7F7F7F7F, 0, 0x7F7F7F7F);
      f4 aB0 = __builtin_amdgcn_mfma_scale_f32_16x16x128_f8f6f4(
          EA[0][2], B4[2], z4, 0, 0, 0, 0x7F7F7F7F, 0, 0x7F7F7F7F);
      f4 aA1 = __builtin_amdgcn_mfma_scale_f32_16x16x128_f8f6f4(
          EA[1][0], B4[0], z4, 0, 0, 0, 0x7F7F7F7F, 0, 0x7F7F7F7F);
      f4 aB1 = __builtin_amdgcn_mfma_scale_f32_16x16x128_f8f6f4(
          EA[1][2], B4[2], z4, 0, 0, 0, 0x7F7F7F7F, 0, 0x7F7F7F7F);
      f4 aA2 = __builtin_amdgcn_mfma_scale_f32_16x16x128_f8f6f4(
          EA[2][0], B4[0], z4, 0, 0, 0, 0x7F7F7F7F, 0, 0x7F7F7F7F);
      f4 aB2 = __builtin_amdgcn_mfma_scale_f32_16x16x128_f8f6f4(
          EA[2][2], B4[2], z4, 0, 0, 0, 0x7F7F7F7F, 0, 0x7F7F7F7F);
      f4 aA3 = __builtin_amdgcn_mfma_scale_f32_16x16x128_f8f6f4(
          EA[3][0], B4[0], z4, 0, 0, 0, 0x7F7F7F7F, 0, 0x7F7F7F7F);
      f4 aB3 = __builtin_amdgcn_mfma_scale_f32_16x16x128_f8f6f4(
          EA[3][2], B4[2], z4, 0, 0, 0, 0x7F7F7F7F, 0, 0x7F7F7F7F);
      aA0 = __builtin_amdgcn_mfma_scale_f32_16x16x128_f8f6f4(
          EA[0][1], B4[1], aA0, 0, 0, 0, 0x7F7F7F7F, 0, 0x7F7F7F7F);
      aB0 = __builtin_amdgcn_mfma_scale_f32_16x16x128_f8f6f4(
          EA[0][3], B4[3], aB0, 0, 0, 0, 0x7F7F7F7F, 0, 0x7F7F7F7F);
      aA1 = __builtin_amdgcn_mfma_scale_f32_16x16x128_f8f6f4(
          EA[1][1], B4[1], aA1, 0, 0, 0, 0x7F7F7F7F, 0, 0x7F7F7F7F);
      aB1 = __builtin_amdgcn_mfma_scale_f32_16x16x128_f8f6f4(
          EA[1][3], B4[3], aB1, 0, 0, 0, 0x7F7F7F7F, 0, 0x7F7F7F7F);
      aA2 = __builtin_amdgcn_mfma_scale_f32_16x16x128_f8f6f4(
          EA[2][1], B4[1], aA2, 0, 0, 0, 0x7F7F7F7F, 0, 0x7F7F7F7F);
      aB2 = __builtin_amdgcn_mfma_scale_f32_16x16x128_f8f6f4(
          EA[2][3], B4[3], aB2, 0, 0, 0, 0x7F7F7F7F, 0, 0x7F7F7F7F);
      aA3 = __builtin_amdgcn_mfma_scale_f32_16x16x128_f8f6f4(
          EA[3][1], B4[1], aA3, 0, 0, 0, 0x7F7F7F7F, 0, 0x7F7F7F7F);
      aB3 = __builtin_amdgcn_mfma_scale_f32_16x16x128_f8f6f4(
          EA[3][3], B4[3], aB3, 0, 0, 0, 0x7F7F7F7F, 0, 0x7F7F7F7F);
      f4 s0 = aA0 + aB0;
      f4 s1 = aA1 + aB1;
      f4 s2 = aA2 + aB2;
      f4 s3 = aA3 + aB3;
      // lane (g,c) holds D[4g+r][c] of tile t2sel; one intra-wave bpermute redistributes
      f4 at = (t2sel == 0) ? s0 : (t2sel == 1) ? s1 : (t2sel == 2) ? s2 : s3;
      float lo = (r2sel & 1) ? at[1] : at[0];
      float hi = (r2sel & 1) ? at[3] : at[2];
      float tot = (r2sel & 2) ? hi : lo;
      float tv = __int_as_float(__builtin_amdgcn_ds_bpermute(sidx, __float_as_int(tot)));
      float nv = m + __logf(tv) + ecur;
      if (sm.f.padsh[t]) nv = alphaR;
      alphaR = nv; ecur = enext;
      float rmx = dpp64max(nv);
      if (lane == 0) sm.f.wred[w] = rmx;
      bar_lgkm();  // B: wred visible; ph safe to overwrite next iter
      m = max8lds(sm.f.wred);  // exact max(alpha_t)
    }

    // epilogue: logZ + gold score (m = exact max alpha_511)
    __syncthreads();
    float ex = __expf(alphaR - m);
#pragma unroll
    for (int off = 1; off < 64; off <<= 1) ex += __shfl_xor(ex, off);
    if (lane == 0) sm.f.wred[w] = ex;
    float sc;
    {
      int t = tid;
      int tg = tgt[b * Tn + t];
      float mt = sm.f.padsh[t] ? 0.f : 1.f;
      sc = eb[(size_t)t * Vn + tg] * mt;
      if (t < Tn - 1) {
        int tg1 = tgt[b * Tn + t + 1];
        float mt1 = sm.f.padsh[t + 1] ? 0.f : 1.f;
        sc += trans[(size_t)tg * Vn + tg1] * mt * mt1;
      }
    }
#pragma unroll
    for (int off = 1; off < 64; off <<= 1) sc += __shfl_xor(sc, off);
    if (lane == 0) sm.f.wred2[w] = sc;
    __syncthreads();
    if (tid == 0) {
      float s = 0.f, gg = 0.f;
      for (int i = 0; i < 8; ++i) { s += sm.f.wred[i]; gg += sm.f.wred2[i]; }
      out_ll[b] = gg - (m + __logf(s));
    }
  } else {
    // ========== VITERBI (8-wave, 1 barrier/step, conflict-free wave-order masks) ==========
    float R = __int_as_float(((const int*)Rp)[0]) * 1.000001f + 1e-4f;
    sm.v.padsh[tid] = pad[b * Tn + tid];
    float vaR = eb[tid];
    sm.v.va2[0][tid] = vaR;
    float ecur = eb[Vn + tid];
    bar_lgkm();

    for (int t = 1; t < Tn; ++t) {
      const int cur = t & 1, prev = cur ^ 1;
      const float* va2p = sm.v.va2[prev];
      float enext = (t + 1 < Tn) ? eb[(size_t)(t + 1) * Vn + tid] : 0.f;  // L3 load first
      // column-order reads: qv[j] = va[64j + lane] (conflict-free), masks in wave order
      float qv[8];
#pragma unroll
      for (int j = 0; j < 8; ++j) qv[j] = va2p[64 * j + lane];
      float mx8 = fmaxf(fmaxf(fmaxf(qv[0], qv[1]), fmaxf(qv[2], qv[3])),
                        fmaxf(fmaxf(qv[4], qv[5]), fmaxf(qv[6], qv[7])));
      float gmax = dpp64max(mx8);
      float thr = gmax - R;
      unsigned long long bm[8];
#pragma unroll
      for (int j = 0; j < 8; ++j) bm[j] = __ballot(qv[j] >= thr);
      float best = -3e38f; int arg = 0;
#pragma unroll
      for (int j = 0; j < 8; ++j) {  // j outer, bit l inner: u = 64j + l ascending
        unsigned long long mask = bm[j];
        while (mask) {
          int l = __ffsll(mask) - 1; mask &= mask - 1;
          int u = 64 * j + l;
          float cnd = va2p[u] + trans[(size_t)u * Vn + tid];
          if (cnd > best) { best = cnd; arg = u; }
        }
      }
      float nv = best + ecur; int bp = arg;
      if (sm.v.padsh[t]) { nv = vaR; bp = tid; }
      bps[((size_t)(t - 1) * Bn + b) * Vn + tid] = (unsigned short)bp;  // floats free
      sm.v.va2[cur][tid] = nv;
      vaR = nv; ecur = enext;
      bar_lgkm();  // single barrier: va2[cur] visible
    }

    // drain bps stores once, then backtrace
    asm volatile("s_waitcnt vmcnt(0)" ::: "memory");
    __syncthreads();

    {
      float val = vaR;
      int idx = tid;
#pragma unroll
      for (int off = 1; off < 64; off <<= 1) {
        float ov = __shfl_xor(val, off);
        int oi = __shfl_xor(idx, off);
        if (ov > val || (ov == val && oi < idx)) { val = ov; idx = oi; }
      }
      if (lane == 0) { sm.v.wvals[w] = val; sm.v.widxs[w] = idx; }
    }
    __syncthreads();
    if (tid == 0) {
      float bv = sm.v.wvals[0]; int bi = sm.v.widxs[0];
      for (int i = 1; i < 8; ++i)
        if (sm.v.wvals[i] > bv || (sm.v.wvals[i] == bv && sm.v.widxs[i] < bi)) {
          bv = sm.v.wvals[i]; bi = sm.v.widxs[i];
        }
      sm.v.lastS = bi;
    }
    __syncthreads();
    int tok = sm.v.lastS;

    // backtrace: rows 510..0, 32-row LDS chunks
    for (int cch = 15; cch >= 0; --cch) {
      int rhi = cch * 32 + 31; if (rhi > 510) rhi = 510;
      int srow = tid >> 4, part = tid & 15;
      int row = cch * 32 + srow;
      if (row <= 510) {
        const uint4* src = (const uint4*)(bps + ((size_t)row * Bn + b) * Vn);
        uint4* dst = (uint4*)&sm.v.bpbuf[srow][0];
#pragma unroll
        for (int qq = 0; qq < 4; ++qq) dst[part * 4 + qq] = src[part * 4 + qq];
      }
      __syncthreads();
      if (tid == 0) {
        int tk = tok;
        for (int rr = rhi; rr >= cch * 32; --rr) {
          sm.v.tokens[rr + 1] = (unsigned short)tk;
          tk = sm.v.bpbuf[rr - cch * 32][tk];
        }
        tok = tk;
      }
      __syncthreads();
    }
    if (tid == 0) sm.v.tokens[0] = (unsigned short)tok;
    __syncthreads();
    out_tok[b * Tn + tid] = (float)sm.v.tokens[tid];
  }
}

extern "C" void kernel_launch(void* const* d_in, const int* in_sizes, int n_in,
                              void* d_out, int out_size, void* d_ws, size_t ws_size,
                              hipStream_t stream) {
  const float* x = (const float*)d_in[0];
  const float* w = (const float*)d_in[1];
  const float* trans = (const float*)d_in[2];
  const int* tgt = (const int*)d_in[3];
  const unsigned char* pad = (const unsigned char*)d_in[4];
  float* out = (float*)d_out;

  char* ws = (char*)d_ws;
  float* Rp = (float*)ws;                                      // 64 B
  unsigned char* E8 = (unsigned char*)(ws + 64);               // 256 KB (reserved 512K)
  unsigned short* bps = (unsigned short*)(ws + 64 + 524288);   // 16.777 MB
  _Float16* WH = (_Float16*)(ws + 64 + 524288 + 16777216);     // 512 KB
  _Float16* WL = (_Float16*)(ws + 64 + 524288 + 16777216 + 524288);  // 512 KB

  float* emis = out;                 // (B,T,V)
  float* out_ll = out + 8388608;     // (B,)
  float* out_tok = out + 8388640;    // (B,T) as float

  (void)hipMemsetAsync(Rp, 0, 4, stream);
  hipLaunchKernelGGL(crf_minmax, dim3(8), dim3(512), 0, stream, trans, (unsigned int*)Rp);
  hipLaunchKernelGGL(crf_build_E8, dim3(128), dim3(256), 0, stream, trans, E8);
  hipLaunchKernelGGL(crf_wsplit, dim3(256), dim3(256), 0, stream, w, WH, WL);
  hipLaunchKernelGGL(crf_gemm, dim3(256), dim3(256), 0, stream, x, WH, WL, emis);
  hipLaunchKernelGGL(crf_scan, dim3(64), dim3(512), 0, stream, emis, trans, E8, Rp,
                     tgt, pad, bps, out_ll, out_tok);
}

// Round 17
// 568.221 us; speedup vs baseline: 1.0428x; 1.0428x over previous
//
#include <hip/hip_runtime.h>

#define Bn 32
#define Tn 512
#define Dn 512
#define Vn 512

typedef float f4 __attribute__((ext_vector_type(4)));
typedef int i8v __attribute__((ext_vector_type(8)));
typedef _Float16 h8f __attribute__((ext_vector_type(8)));

__device__ __forceinline__ float max8lds(const float* p) {
  float4 a = *(const float4*)p;
  float4 b = *(const float4*)(p + 4);
  return fmaxf(fmaxf(fmaxf(a.x, a.y), fmaxf(a.z, a.w)),
               fmaxf(fmaxf(b.x, b.y), fmaxf(b.z, b.w)));
}

// 64-lane max via DPP (row_shr 1/2/4/8 + bcast15/31), result broadcast via readlane
__device__ __forceinline__ float dpp64max(float x) {
  int t;
  t = __builtin_amdgcn_update_dpp(__float_as_int(x), __float_as_int(x), 0x111, 0xF, 0xF, false);
  x = fmaxf(x, __int_as_float(t));
  t = __builtin_amdgcn_update_dpp(__float_as_int(x), __float_as_int(x), 0x112, 0xF, 0xF, false);
  x = fmaxf(x, __int_as_float(t));
  t = __builtin_amdgcn_update_dpp(__float_as_int(x), __float_as_int(x), 0x114, 0xF, 0xF, false);
  x = fmaxf(x, __int_as_float(t));
  t = __builtin_amdgcn_update_dpp(__float_as_int(x), __float_as_int(x), 0x118, 0xF, 0xF, false);
  x = fmaxf(x, __int_as_float(t));
  t = __builtin_amdgcn_update_dpp(__float_as_int(x), __float_as_int(x), 0x142, 0xF, 0xF, false);
  x = fmaxf(x, __int_as_float(t));
  t = __builtin_amdgcn_update_dpp(__float_as_int(x), __float_as_int(x), 0x143, 0xF, 0xF, false);
  x = fmaxf(x, __int_as_float(t));
  return __int_as_float(__builtin_amdgcn_readlane(__float_as_int(x), 63));
}

// raw barrier: LDS-visibility only (no vmcnt drain -> global ops float across steps)
__device__ __forceinline__ void bar_lgkm() {
  asm volatile("s_waitcnt lgkmcnt(0)" ::: "memory");
  __builtin_amdgcn_s_barrier();
}

// ---- f32 -> OCP e4m3fn, round-to-nearest-even (x >= 0 assumed) ----
__device__ __forceinline__ unsigned int f32_to_e4m3(float x) {
  x = fminf(x, 448.0f);
  unsigned int bits = __float_as_uint(x);
  int e = (int)((bits >> 23) & 0xFF) - 127;
  if (e < -6) {
    return (unsigned int)__float2int_rn(x * 512.0f);
  }
  unsigned int man = bits & 0x7FFFFF;
  int te = e + 7;
  unsigned int r = man >> 20;
  unsigned int rem = man & 0xFFFFF;
  if (rem > 0x80000u || (rem == 0x80000u && (r & 1u))) r++;
  if (r == 8u) { r = 0u; te++; }
  if (te > 15) { te = 15; r = 6u; }
  unsigned int byte = ((unsigned int)te << 3) | r;
  if (byte > 0x7Eu) byte = 0x7Eu;
  return byte;
}

// fast path: HW packed fp8 convert (branch-free); fallback = software RNE
__device__ __forceinline__ unsigned int cvt_e4m3_fast(float p) {
#if __has_builtin(__builtin_amdgcn_cvt_pk_fp8_f32)
  return (unsigned int)(__builtin_amdgcn_cvt_pk_fp8_f32(p, p, 0, false) & 0xFF);
#else
  return f32_to_e4m3(p);
#endif
}

// ---- merged prep + GEMM kernel, 256 threads/block ----
// blocks 0..255   : emissions GEMM (split-f16 MFMA, in-kernel W split), m0 = bid*64
// blocks 256..383 : E8 build (exp(trans) fp8 A-fragments), fid = bid-256
// blocks 384..391 : minmax partial -> plain store Rp[bid-384] (no atomic/memset)
union PG {
  struct {
    __align__(16) h8f XfH[4][64], XfL[4][64];    // 8 KB
    __align__(16) h8f WfH[32][64], WfL[32][64];  // 64 KB
  } g;
  struct { float tl[32][17]; } e;
  struct { float smn[4][64], smx[4][64]; } m;
};

__global__ __launch_bounds__(256) void crf_prep_gemm(
    const float* __restrict__ X, const float* __restrict__ Wt,
    const float* __restrict__ trans, unsigned char* __restrict__ E8,
    float* __restrict__ Rp, float* __restrict__ C) {
  __shared__ PG sm;
  const int bid = (int)blockIdx.x;
  const int tid = threadIdx.x;

  if (bid < 256) {
    // ================== GEMM role ==================
    const int m0 = bid * 64;
    const int wv = tid >> 6, lane = tid & 63;
    const int g = lane >> 4, cc = lane & 15;
    const int srow = tid >> 2;                // 0..63
    const int sc0 = (tid & 3) * 8;            // k-chunk 0/8/16/24
    const int p = (tid & 3) * 16 + ((tid >> 2) & 15);  // fragment slot
    f4 acc[32];
#pragma unroll
    for (int i = 0; i < 32; ++i) acc[i] = (f4)(0.f);

    for (int k0 = 0; k0 < Dn; k0 += 32) {
      __syncthreads();
      {
        const float* xp = X + (size_t)(m0 + srow) * Dn + k0 + sc0;
        float4 xa = *(const float4*)xp;
        float4 xb = *(const float4*)(xp + 4);
        float xs[8] = {xa.x, xa.y, xa.z, xa.w, xb.x, xb.y, xb.z, xb.w};
        _Float16 hh[8], ll[8];
#pragma unroll
        for (int i = 0; i < 8; ++i) {
          hh[i] = (_Float16)xs[i];
          ll[i] = (_Float16)(xs[i] - (float)hh[i]);
        }
        sm.g.XfH[tid >> 6][p] = *(h8f*)hh;
        sm.g.XfL[tid >> 6][p] = *(h8f*)ll;
#pragma unroll
        for (int i = 0; i < 8; ++i) {
          int r = i * 64 + srow;
          const float* wp = Wt + (size_t)r * Dn + k0 + sc0;
          float4 wa = *(const float4*)wp;
          float4 wb = *(const float4*)(wp + 4);
          float wsv[8] = {wa.x, wa.y, wa.z, wa.w, wb.x, wb.y, wb.z, wb.w};
          _Float16 wh[8], wl[8];
#pragma unroll
          for (int q = 0; q < 8; ++q) {
            wh[q] = (_Float16)wsv[q];
            wl[q] = (_Float16)(wsv[q] - (float)wh[q]);
          }
          sm.g.WfH[i * 4 + (tid >> 6)][p] = *(h8f*)wh;
          sm.g.WfL[i * 4 + (tid >> 6)][p] = *(h8f*)wl;
        }
      }
      __syncthreads();
      h8f aH = sm.g.XfH[wv][lane];
      h8f aL = sm.g.XfL[wv][lane];
#pragma unroll
      for (int nt = 0; nt < 32; ++nt) {
        h8f bH = sm.g.WfH[nt][lane];
        h8f bL = sm.g.WfL[nt][lane];
        acc[nt] = __builtin_amdgcn_mfma_f32_16x16x32_f16(aH, bH, acc[nt], 0, 0, 0);
        acc[nt] = __builtin_amdgcn_mfma_f32_16x16x32_f16(aH, bL, acc[nt], 0, 0, 0);
        acc[nt] = __builtin_amdgcn_mfma_f32_16x16x32_f16(aL, bH, acc[nt], 0, 0, 0);
        acc[nt] = __builtin_amdgcn_mfma_f32_16x16x32_f16(aL, bL, acc[nt], 0, 0, 0);
      }
    }
#pragma unroll
    for (int nt = 0; nt < 32; ++nt)
#pragma unroll
      for (int r = 0; r < 4; ++r)
        C[(size_t)(m0 + wv * 16 + 4 * g + r) * Vn + nt * 16 + cc] = acc[nt][r];
  } else if (bid < 384) {
    // ================== E8 role ==================
    const int fid = bid - 256;             // 0..127 = vt*4 + kc
    const int vt = fid >> 2, kc = fid & 3;
    const int lane = tid >> 2;
    const int j0 = (tid & 3) * 8;
    const int v = vt * 16 + (lane & 15);
    const int ubase = kc * 128 + (lane >> 4) * 32 + j0;
    unsigned long long pack = 0;
#pragma unroll
    for (int s = 0; s < 8; ++s) {
      float e = __expf(trans[(size_t)(ubase + s) * Vn + v]);
      pack |= (unsigned long long)f32_to_e4m3(e) << (8 * s);
    }
    *(unsigned long long*)(E8 + (size_t)fid * 2048 + lane * 32 + j0) = pack;
  } else {
    // ================== minmax role (plain store, poison-proof) ==================
    const int blk = bid - 384;             // 0..7
    const int c = tid & 63;
    const int seg = tid >> 6;              // 0..3, each covers 128 rows
    const int col = blk * 64 + c;
    float mn = 3e38f, mx = -3e38f;
    for (int u = seg * 128; u < seg * 128 + 128; ++u) {
      float t = trans[(size_t)u * Vn + col];
      mn = fminf(mn, t); mx = fmaxf(mx, t);
    }
    sm.m.smn[seg][c] = mn; sm.m.smx[seg][c] = mx;
    __syncthreads();
    if (seg == 0) {
#pragma unroll
      for (int i = 1; i < 4; ++i) {
        mn = fminf(mn, sm.m.smn[i][c]);
        mx = fmaxf(mx, sm.m.smx[i][c]);
      }
      float r = dpp64max(mx - mn);  // r >= 0, uniform in wave 0
      if (c == 0) Rp[blk] = r;      // plain store overwrites any garbage
    }
  }
}

// ---- shared-memory union: forward vs viterbi roles ----
union SM {
  struct {
    __align__(16) unsigned char ph[Vn];   // fp8 p broadcast (512 B)
    __align__(16) float wred[8];
    __align__(16) float wred2[8];
    unsigned char padsh[Tn];
  } f;
  struct {
    __align__(16) float va2[2][Vn];
    __align__(16) unsigned short bpbuf[32][Vn];
    unsigned short tokens[Tn];
    __align__(16) float wvals[8];
    int widxs[8];
    unsigned char padsh[Tn];
    int lastS;
  } v;
};

// ---- fused scan: blocks 0..31 forward(logZ,loglik); 32..63 viterbi+backtrace ----
__global__ __launch_bounds__(512, 2) void crf_scan(
    const float* __restrict__ emis, const float* __restrict__ trans,
    const unsigned char* __restrict__ E8, const float* __restrict__ Rp,
    const int* __restrict__ tgt, const unsigned char* __restrict__ pad,
    unsigned short* __restrict__ bps, float* __restrict__ out_ll,
    float* __restrict__ out_tok) {
  __shared__ SM sm;

  const int tid = threadIdx.x;
  const int b = blockIdx.x & 31;
  const int role = blockIdx.x >> 5;
  const float* eb = emis + (size_t)b * Tn * Vn;
  const int w = tid >> 6;
  const int lane = tid & 63;

  if (role == 0) {
    // ========== FORWARD (MX-FP8 MFMA K=128, exact-m, 2-deep MFMA chains) ==========
    const int g = lane >> 4, c = lane & 15;
    const int t2sel = c >> 2, r2sel = c & 3;
    const int sidx = ((16 * ((lane >> 2) & 3)) + 4 * (lane >> 4) + (lane & 3)) << 2;
    i8v EA[4][4];
    {
      const i8v* E8v = (const i8v*)E8;
#pragma unroll
      for (int vt2 = 0; vt2 < 4; ++vt2)
#pragma unroll
        for (int kc = 0; kc < 4; ++kc)
          EA[vt2][kc] = E8v[((4 * w + vt2) * 4 + kc) * 64 + lane];
    }
    sm.f.padsh[tid] = pad[b * Tn + tid];
    float alphaR = eb[tid];
    float ecur = eb[Vn + tid];
    {
      float r = dpp64max(alphaR);
      if (lane == 0) sm.f.wred[w] = r;
    }
    bar_lgkm();
    float m = max8lds(sm.f.wred);  // exact max(alpha_{t-1})

    const f4 z4 = (f4)(0.f);
    for (int t = 1; t < Tn; ++t) {
      float p = __expf(alphaR - m);            // p in (0, 1]
      sm.f.ph[tid] = (unsigned char)cvt_e4m3_fast(p);
      bar_lgkm();  // A: ph visible
      float enext = (t + 1 < Tn) ? eb[(size_t)(t + 1) * Vn + tid] : 0.f;
      const uint4* phq = (const uint4*)sm.f.ph;
      i8v B4[4];
#pragma unroll
      for (int kc = 0; kc < 4; ++kc) {
        union { uint4 u[2]; i8v v; } bu;
        bu.u[0] = phq[kc * 8 + g * 2];
        bu.u[1] = phq[kc * 8 + g * 2 + 1];
        B4[kc] = bu.v;
      }
      // 8 accumulators, 2-deep chains (kc{0,1} -> A, kc{2,3} -> B), C=z4 init
      f4 aA0 = __builtin_amdgcn_mfma_scale_f32_16x16x128_f8f6f4(
          EA[0][0], B4[0], z4, 0, 0, 0, 0x7F7F7F7F, 0, 0x7F7F7F7F);
      f4 aB0 = __builtin_amdgcn_mfma_scale_f32_16x16x128_f8f6f4(
          EA[0][2], B4[2], z4, 0, 0, 0, 0x7F7F7F7F, 0, 0x7F7F7F7F);
      f4 aA1 = __builtin_amdgcn_mfma_scale_f32_16x16x128_f8f6f4(
          EA[1][0], B4[0], z4, 0, 0, 0, 0x7F7F7F7F, 0, 0x7F7F7F7F);
      f4 aB1 = __builtin_amdgcn_mfma_scale_f32_16x16x128_f8f6f4(
          EA[1][2], B4[2], z4, 0, 0, 0, 0x7F7F7F7F, 0, 0x7F7F7F7F);
      f4 aA2 = __builtin_amdgcn_mfma_scale_f32_16x16x128_f8f6f4(
          EA[2][0], B4[0], z4, 0, 0, 0, 0x7F7F7F7F, 0, 0x7F7F7F7F);
      f4 aB2 = __builtin_amdgcn_mfma_scale_f32_16x16x128_f8f6f4(
          EA[2][2], B4[2], z4, 0, 0, 0, 0x7F7F7F7F, 0, 0x7F7F7F7F);
      f4 aA3 = __builtin_amdgcn_mfma_scale_f32_16x16x128_f8f6f4(
          EA[3][0], B4[0], z4, 0, 0, 0, 0x7F7F7F7F, 0, 0x7F7F7F7F);
      f4 aB3 = __builtin_amdgcn_mfma_scale_f32_16x16x128_f8f6f4(
          EA[3][2], B4[2], z4, 0, 0, 0, 0x7F7F7F7F, 0, 0x7F7F7F7F);
      aA0 = __builtin_amdgcn_mfma_scale_f32_16x16x128_f8f6f4(
          EA[0][1], B4[1], aA0, 0, 0, 0, 0x7F7F7F7F, 0, 0x7F7F7F7F);
      aB0 = __builtin_amdgcn_mfma_scale_f32_16x16x128_f8f6f4(
          EA[0][3], B4[3], aB0, 0, 0, 0, 0x7F7F7F7F, 0, 0x7F7F7F7F);
      aA1 = __builtin_amdgcn_mfma_scale_f32_16x16x128_f8f6f4(
          EA[1][1], B4[1], aA1, 0, 0, 0, 0x7F7F7F7F, 0, 0x7F7F7F7F);
      aB1 = __builtin_amdgcn_mfma_scale_f32_16x16x128_f8f6f4(
          EA[1][3], B4[3], aB1, 0, 0, 0, 0x7F7F7F7F, 0, 0x7F7F7F7F);
      aA2 = __builtin_amdgcn_mfma_scale_f32_16x16x128_f8f6f4(
          EA[2][1], B4[1], aA2, 0, 0, 0, 0x7F7F7F7F, 0, 0x7F7F7F7F);
      aB2 = __builtin_amdgcn_mfma_scale_f32_16x16x128_f8f6f4(
          EA[2][3], B4[3], aB2, 0, 0, 0, 0x7F7F7F7F, 0, 0x7F7F7F7F);
      aA3 = __builtin_amdgcn_mfma_scale_f32_16x16x128_f8f6f4(
          EA[3][1], B4[1], aA3, 0, 0, 0, 0x7F7F7F7F, 0, 0x7F7F7F7F);
      aB3 = __builtin_amdgcn_mfma_scale_f32_16x16x128_f8f6f4(
          EA[3][3], B4[3], aB3, 0, 0, 0, 0x7F7F7F7F, 0, 0x7F7F7F7F);
      f4 s0 = aA0 + aB0;
      f4 s1 = aA1 + aB1;
      f4 s2 = aA2 + aB2;
      f4 s3 = aA3 + aB3;
      // lane (g,c) holds D[4g+r][c] of tile t2sel; one intra-wave bpermute redistributes
      f4 at = (t2sel == 0) ? s0 : (t2sel == 1) ? s1 : (t2sel == 2) ? s2 : s3;
      float lo = (r2sel & 1) ? at[1] : at[0];
      float hi = (r2sel & 1) ? at[3] : at[2];
      float tot = (r2sel & 2) ? hi : lo;
      float tv = __int_as_float(__builtin_amdgcn_ds_bpermute(sidx, __float_as_int(tot)));
      float nv = m + __logf(tv) + ecur;
      if (sm.f.padsh[t]) nv = alphaR;
      alphaR = nv; ecur = enext;
      float rmx = dpp64max(nv);
      if (lane == 0) sm.f.wred[w] = rmx;
      bar_lgkm();  // B: wred visible; ph safe to overwrite next iter
      m = max8lds(sm.f.wred);  // exact max(alpha_t)
    }

    // epilogue: logZ + gold score (m = exact max alpha_511)
    __syncthreads();
    float ex = __expf(alphaR - m);
#pragma unroll
    for (int off = 1; off < 64; off <<= 1) ex += __shfl_xor(ex, off);
    if (lane == 0) sm.f.wred[w] = ex;
    float sc;
    {
      int t = tid;
      int tg = tgt[b * Tn + t];
      float mt = sm.f.padsh[t] ? 0.f : 1.f;
      sc = eb[(size_t)t * Vn + tg] * mt;
      if (t < Tn - 1) {
        int tg1 = tgt[b * Tn + t + 1];
        float mt1 = sm.f.padsh[t + 1] ? 0.f : 1.f;
        sc += trans[(size_t)tg * Vn + tg1] * mt * mt1;
      }
    }
#pragma unroll
    for (int off = 1; off < 64; off <<= 1) sc += __shfl_xor(sc, off);
    if (lane == 0) sm.f.wred2[w] = sc;
    __syncthreads();
    if (tid == 0) {
      float s = 0.f, gg = 0.f;
      for (int i = 0; i < 8; ++i) { s += sm.f.wred[i]; gg += sm.f.wred2[i]; }
      out_ll[b] = gg - (m + __logf(s));
    }
  } else {
    // ========== VITERBI (8-wave, 1 barrier/step, conflict-free wave-order masks) ==========
    float R;
    {
      float4 r0 = *(const float4*)Rp;
      float4 r1 = *(const float4*)(Rp + 4);
      R = fmaxf(fmaxf(fmaxf(r0.x, r0.y), fmaxf(r0.z, r0.w)),
                fmaxf(fmaxf(r1.x, r1.y), fmaxf(r1.z, r1.w)));
      R = R * 1.000001f + 1e-4f;
    }
    sm.v.padsh[tid] = pad[b * Tn + tid];
    float vaR = eb[tid];
    sm.v.va2[0][tid] = vaR;
    float ecur = eb[Vn + tid];
    bar_lgkm();

    for (int t = 1; t < Tn; ++t) {
      const int cur = t & 1, prev = cur ^ 1;
      const float* va2p = sm.v.va2[prev];
      float enext = (t + 1 < Tn) ? eb[(size_t)(t + 1) * Vn + tid] : 0.f;  // L3 load first
      // column-order reads: qv[j] = va[64j + lane] (conflict-free), masks in wave order
      float qv[8];
#pragma unroll
      for (int j = 0; j < 8; ++j) qv[j] = va2p[64 * j + lane];
      float mx8 = fmaxf(fmaxf(fmaxf(qv[0], qv[1]), fmaxf(qv[2], qv[3])),
                        fmaxf(fmaxf(qv[4], qv[5]), fmaxf(qv[6], qv[7])));
      float gmax = dpp64max(mx8);
      float thr = gmax - R;
      unsigned long long bm[8];
#pragma unroll
      for (int j = 0; j < 8; ++j) bm[j] = __ballot(qv[j] >= thr);
      float best = -3e38f; int arg = 0;
#pragma unroll
      for (int j = 0; j < 8; ++j) {  // j outer, bit l inner: u = 64j + l ascending
        unsigned long long mask = bm[j];
        while (mask) {
          int l = __ffsll(mask) - 1; mask &= mask - 1;
          int u = 64 * j + l;
          float cnd = va2p[u] + trans[(size_t)u * Vn + tid];
          if (cnd > best) { best = cnd; arg = u; }
        }
      }
      float nv = best + ecur; int bp = arg;
      if (sm.v.padsh[t]) { nv = vaR; bp = tid; }
      bps[((size_t)(t - 1) * Bn + b) * Vn + tid] = (unsigned short)bp;  // floats free
      sm.v.va2[cur][tid] = nv;
      vaR = nv; ecur = enext;
      bar_lgkm();  // single barrier: va2[cur] visible
    }

    // drain bps stores once, then backtrace
    asm volatile("s_waitcnt vmcnt(0)" ::: "memory");
    __syncthreads();

    {
      float val = vaR;
      int idx = tid;
#pragma unroll
      for (int off = 1; off < 64; off <<= 1) {
        float ov = __shfl_xor(val, off);
        int oi = __shfl_xor(idx, off);
        if (ov > val || (ov == val && oi < idx)) { val = ov; idx = oi; }
      }
      if (lane == 0) { sm.v.wvals[w] = val; sm.v.widxs[w] = idx; }
    }
    __syncthreads();
    if (tid == 0) {
      float bv = sm.v.wvals[0]; int bi = sm.v.widxs[0];
      for (int i = 1; i < 8; ++i)
        if (sm.v.wvals[i] > bv || (sm.v.wvals[i] == bv && sm.v.widxs[i] < bi)) {
          bv = sm.v.wvals[i]; bi = sm.v.widxs[i];
        }
      sm.v.lastS = bi;
    }
    __syncthreads();
    int tok = sm.v.lastS;

    // backtrace: rows 510..0, 32-row LDS chunks
    for (int cch = 15; cch >= 0; --cch) {
      int rhi = cch * 32 + 31; if (rhi > 510) rhi = 510;
      int srow = tid >> 4, part = tid & 15;
      int row = cch * 32 + srow;
      if (row <= 510) {
        const uint4* src = (const uint4*)(bps + ((size_t)row * Bn + b) * Vn);
        uint4* dst = (uint4*)&sm.v.bpbuf[srow][0];
#pragma unroll
        for (int qq = 0; qq < 4; ++qq) dst[part * 4 + qq] = src[part * 4 + qq];
      }
      __syncthreads();
      if (tid == 0) {
        int tk = tok;
        for (int rr = rhi; rr >= cch * 32; --rr) {
          sm.v.tokens[rr + 1] = (unsigned short)tk;
          tk = sm.v.bpbuf[rr - cch * 32][tk];
        }
        tok = tk;
      }
      __syncthreads();
    }
    if (tid == 0) sm.v.tokens[0] = (unsigned short)tok;
    __syncthreads();
    out_tok[b * Tn + tid] = (float)sm.v.tokens[tid];
  }
}

extern "C" void kernel_launch(void* const* d_in, const int* in_sizes, int n_in,
                              void* d_out, int out_size, void* d_ws, size_t ws_size,
                              hipStream_t stream) {
  const float* x = (const float*)d_in[0];
  const float* w = (const float*)d_in[1];
  const float* trans = (const float*)d_in[2];
  const int* tgt = (const int*)d_in[3];
  const unsigned char* pad = (const unsigned char*)d_in[4];
  float* out = (float*)d_out;

  char* ws = (char*)d_ws;
  float* Rp = (float*)ws;                                    // 64 B (8 partials)
  unsigned char* E8 = (unsigned char*)(ws + 64);             // 256 KB fp8 fragments
  unsigned short* bps = (unsigned short*)(ws + 64 + 524288); // ~16.7 MB

  float* emis = out;                 // (B,T,V)
  float* out_ll = out + 8388608;     // (B,)
  float* out_tok = out + 8388640;    // (B,T) as float

  hipLaunchKernelGGL(crf_prep_gemm, dim3(392), dim3(256), 0, stream,
                     x, w, trans, E8, Rp, emis);
  hipLaunchKernelGGL(crf_scan, dim3(64), dim3(512), 0, stream, emis, trans, E8, Rp,
                     tgt, pad, bps, out_ll, out_tok);
}